// Round 15
// baseline (155.903 us; speedup 1.0000x reference)
//
#include <hip/hip_runtime.h>
#include <math.h>

// Problem constants (from reference setup_inputs)
#define L0      3072
#define BATCH   1024
#define NNEG    512

// -------- workspace layout (float indices into d_ws) --------
// X0 : bf16[393216]            (feat @ w_self_0, bf16)
// Y0 : bf16[393216]            = X0 + 393216 elems
// R  : float @ 1966080 (3072*256)  layer-1 output, normalized
// spPosPart @ 2752512 (float[32]), spNegPart @ 2752640 (float[256]),
// rankPart @ 2753664 (int[8*1024])

__device__ __forceinline__ float bf2f(unsigned short u) {
  return __uint_as_float(((unsigned)u) << 16);
}
__device__ __forceinline__ void store_out(float v, float* p) { *p = v; }
__device__ __forceinline__ void store_out(float v, unsigned short* p) {
  unsigned x = __float_as_uint(v);                 // f32 -> bf16 RNE
  *p = (unsigned short)((x + 0x7fff + ((x >> 16) & 1)) >> 16);
}

// Half-split matmul, 6 rows x 256 cols per 512-thread block. (unchanged, R7)
template<int K, int AW, int HOFF, bool NORM, typename OutT>
__global__ __launch_bounds__(512) void k_mm(
    const float* __restrict__ Ain,
    const float* __restrict__ W0, const float* __restrict__ W1,
    OutT* __restrict__ Out, const int ldo, const int outHalfOff) {
  __shared__ float AT[6 * AW];
  __shared__ float rs[8][3];
  const int t = threadIdx.x;
  const int base = blockIdx.x * 6;
  {
    const float4* __restrict__ src = (const float4*)(Ain + base * AW);
    float4* __restrict__ dst = (float4*)AT;
    for (int idx = t; idx < 6 * AW / 4; idx += 512) dst[idx] = src[idx];
  }
  __syncthreads();

  const int wave = t >> 6;
  const int half = wave >> 2;
  const int colg = (wave >> 1) & 1;
  const int rowg = wave & 1;
  const int rg = rowg * 3;
  const int col = colg * 64 + (t & 63);
  const float* __restrict__ W = (half ? W1 : W0) + col;
  const float* __restrict__ A0 = AT + rg * AW + half * HOFF;

  float acc[3] = {0.f, 0.f, 0.f};
#pragma unroll 4
  for (int d = 0; d < K; d += 4) {
    float4 a[3];
#pragma unroll
    for (int r = 0; r < 3; ++r) a[r] = *(const float4*)&A0[r * AW + d];
    float w[4];
#pragma unroll
    for (int i2 = 0; i2 < 4; ++i2) w[i2] = W[(d + i2) * 128];
#pragma unroll
    for (int i2 = 0; i2 < 4; ++i2)
#pragma unroll
      for (int r = 0; r < 3; ++r)
        acc[r] = fmaf(((const float*)&a[r])[i2], w[i2], acc[r]);
  }

  float scale[3] = {1.f, 1.f, 1.f};
  if (NORM) {
    float p[3];
#pragma unroll
    for (int r = 0; r < 3; ++r) p[r] = acc[r] * acc[r];
#pragma unroll
    for (int off = 32; off > 0; off >>= 1)
#pragma unroll
      for (int r = 0; r < 3; ++r) p[r] += __shfl_xor(p[r], off, 64);
    if ((t & 63) == 0) { rs[wave][0] = p[0]; rs[wave][1] = p[1]; rs[wave][2] = p[2]; }
    __syncthreads();
#pragma unroll
    for (int r = 0; r < 3; ++r) {
      const float s = rs[rowg][r] + rs[rowg + 2][r] + rs[rowg + 4][r] + rs[rowg + 6][r];
      scale[r] = rsqrtf(fmaxf(s, 1e-12f));
    }
  }
  OutT* __restrict__ O = Out + half * outHalfOff;
#pragma unroll
  for (int r = 0; r < 3; ++r)
    store_out(acc[r] * scale[r], &O[(base + rg + r) * ldo + col]);
}

// FUSED aggregate + mm2 + L2-norm, v4 = R14's winning v1-structure+prefetch
// at 2 nodes/block for RESIDENCY. 1536 blocks x 512 threads, 20 tasks,
// ~35 KB LDS -> 4 blocks/CU = 32 waves/CU (the wave-slot cap; 2x R14's 16,
// whose OccupancyPercent was pinned at ~30%). Wave w runs tasks {w, w+8}
// (+{w+16} for w<4) with the BYTE-IDENTICAL per-task prefetch-then-consume
// chain of R14 (R13's regression was killing the task streams, not LDS
// size). H-build: same ascending-jj sums -> H bit-identical. mm2: 2 rows x
// 256 cols = exactly 512 outputs, 1/thread, same fmaf chain, same 4-term
// norm grouping -> R BIT-IDENTICAL -> k_neg tie semantics untouched.
__global__ __launch_bounds__(512) void k_aggmm(
    const unsigned short* __restrict__ X0, const unsigned short* __restrict__ Y0,
    const int* __restrict__ nb0, const int* __restrict__ nb1,
    const int* __restrict__ nb2,
    const float* __restrict__ ws1, const float* __restrict__ wn1,
    float* __restrict__ R) {
  __shared__ float gB[20][128], gC[20][128], gD[20][128];  // 30.7 KB
  __shared__ float HT[2 * 512];                            // 4 KB
  __shared__ float rs[8];
  const int t = threadIdx.x;
  const int wave = t >> 6, lam = t & 63;
  const int base = blockIdx.x * 2;
  const int c8 = lam & 15, sub = lam >> 4;

  // ---- agg phase: 20 tasks, wave-strided, prefetch-then-consume ----
#pragma unroll
  for (int k = 0; k < 3; ++k) {
    const int tau = wave + k * 8;            // 0..19 for k<2 or wave<4
    if (k < 2 || wave < 4) {
      const int li = tau / 10, j = tau - li * 10;
      const int r = (base + li) * 10 + j;
      int myidx = 0;
      if (lam < 25) myidx = nb2[r * 25 + lam];
      else if (lam == 25) myidx = nb1[r];

      // phase 1: issue ALL loads (7 gather rows + the B/C row)
      float4 raw[7];
#pragma unroll
      for (int m = 0; m < 7; ++m) {
        const int kk = sub + 4 * m;
        const int ridx = __shfl(myidx, kk, 64);
        if (kk < 25) raw[m] = *(const float4*)(Y0 + ridx * 128 + c8 * 8);
      }
      const int r1 = __shfl(myidx, 25, 64);
      float4 rawBC;
      if (sub == 0)      rawBC = *(const float4*)(Y0 + r1 * 128 + c8 * 8);
      else if (sub == 1) rawBC = *(const float4*)(X0 + r1 * 128 + c8 * 8);

      // phase 2: consume in ascending m order (bit-identical chain)
      float d8[8];
#pragma unroll
      for (int e = 0; e < 8; ++e) d8[e] = 0.f;
#pragma unroll
      for (int m = 0; m < 7; ++m) {
        const int kk = sub + 4 * m;
        if (kk < 25) {
          const unsigned short* u = (const unsigned short*)&raw[m];
#pragma unroll
          for (int e = 0; e < 8; ++e) d8[e] += bf2f(u[e]);
        }
      }
#pragma unroll
      for (int e = 0; e < 8; ++e) d8[e] += __shfl_xor(d8[e], 16, 64);
#pragma unroll
      for (int e = 0; e < 8; ++e) d8[e] += __shfl_xor(d8[e], 32, 64);

      if (sub == 0) {
#pragma unroll
        for (int e = 0; e < 8; ++e) gD[tau][c8 * 8 + e] = fmaxf(d8[e] * 0.04f, 0.f);
        const unsigned short* u = (const unsigned short*)&rawBC;
#pragma unroll
        for (int e = 0; e < 8; ++e) gB[tau][c8 * 8 + e] = bf2f(u[e]);
      } else if (sub == 1) {
        const unsigned short* u = (const unsigned short*)&rawBC;
#pragma unroll
        for (int e = 0; e < 8; ++e) gC[tau][c8 * 8 + e] = fmaxf(bf2f(u[e]), 0.f);
      }
    }
  }
  __syncthreads();

  // ---- H-build: threads t<256 = 2 nodes x 128 cols, ascending-jj sums ----
  if (t < 256) {
    const int li = t >> 7, c = t & 127;
    const int n0 = nb0[base + li];
    float sB = 0.f, sC = 0.f, sD = 0.f;
#pragma unroll
    for (int jj = 0; jj < 10; ++jj) {
      sB += gB[li * 10 + jj][c];
      sC += gC[li * 10 + jj][c];
      sD += gD[li * 10 + jj][c];
    }
    HT[li * 512 + c]       = fmaxf(bf2f(X0[n0 * 128 + c]), 0.f);
    HT[li * 512 + 128 + c] = fmaxf(sB * 0.1f, 0.f);
    HT[li * 512 + 256 + c] = sC * 0.1f;
    HT[li * 512 + 384 + c] = sD * 0.1f;
  }
  __syncthreads();

  // ---- mm2 phase: 2 rows x 256 cols = 512 outputs, identical chain ----
  const int half = wave >> 2;
  const int colg = (wave >> 1) & 1;
  const int rowg = wave & 1;
  const int col = colg * 64 + lam;
  const float* __restrict__ W = (half ? wn1 : ws1) + col;
  const float* __restrict__ A0 = HT + rowg * 512 + half * 256;

  float acc = 0.f;
#pragma unroll 4
  for (int d = 0; d < 256; d += 4) {
    const float4 a = *(const float4*)&A0[d];
    float w[4];
#pragma unroll
    for (int i2 = 0; i2 < 4; ++i2) w[i2] = W[(d + i2) * 128];
#pragma unroll
    for (int i2 = 0; i2 < 4; ++i2)
      acc = fmaf(((const float*)&a)[i2], w[i2], acc);
  }

  float p = acc * acc;
#pragma unroll
  for (int off = 32; off > 0; off >>= 1) p += __shfl_xor(p, off, 64);
  if (lam == 0) rs[wave] = p;
  __syncthreads();
  {
    const float s = rs[rowg] + rs[rowg + 2] + rs[rowg + 4] + rs[rowg + 6];
    const float scale = rsqrtf(fmaxf(s, 1e-12f));
    R[(base + rowg) * 256 + half * 128 + col] = acc * scale;
  }
}

__device__ __forceinline__ float softplusf(float x) {
  return fmaxf(x, 0.f) + log1pf(expf(-fabsf(x)));
}

// neg_aff v11 (unchanged from the 153.1 winner). LDS-staged B, zero global
// inner-loop ops, zero global atomics.
__global__ __launch_bounds__(512) void k_neg(
    const float* __restrict__ O,
    const int* __restrict__ src_idx, const int* __restrict__ pos_idx,
    const int* __restrict__ neg_idx,
    float* __restrict__ out_src, int* __restrict__ rankPart,
    float* __restrict__ spPosPart, float* __restrict__ spNegPart) {
  __shared__ float SP[64 * 260];     // rows [0,32) src, [32,64) pos (padded)
  __shared__ float BT[256 * 64];     // d-major transposed neg tile (exact bits)
  __shared__ float affL[32];
  __shared__ int cntL[32];
  __shared__ float wsum[16];
  const int t = threadIdx.x;
  const int bid = blockIdx.x;
  const int rowBase = (bid >> 3) * 32;  // 32 row-tiles of 32
  const int colBase = (bid & 7) * 64;   // 8 col-tiles of 64
  const bool first = ((bid & 7) == 0);

  {
    const float4* __restrict__ s4 = (const float4*)O;
#pragma unroll
    for (int idx = t; idx < 64 * 64; idx += 512) {
      const int row = idx >> 6, c4 = idx & 63;
      const int rid = (row < 32) ? src_idx[rowBase + row]
                                 : pos_idx[rowBase + row - 32];
      *(float4*)&SP[row * 260 + c4 * 4] = s4[rid * 64 + c4];
    }
  }
  {
    const float4* __restrict__ s4 = (const float4*)O;
#pragma unroll
    for (int idx = t; idx < 64 * 64; idx += 512) {
      const int j = idx & 63, c4 = idx >> 6;
      const float4 v = s4[neg_idx[colBase + j] * 64 + c4];
      BT[(4 * c4 + 0) * 64 + j] = v.x;
      BT[(4 * c4 + 1) * 64 + j] = v.y;
      BT[(4 * c4 + 2) * 64 + j] = v.z;
      BT[(4 * c4 + 3) * 64 + j] = v.w;
    }
  }
  if (first) {
    const float4* __restrict__ s4 = (const float4*)O;
    float4* __restrict__ d4o = (float4*)out_src;
#pragma unroll
    for (int idx = t; idx < 32 * 64; idx += 512) {
      const int rr = idx >> 6, c4 = idx & 63;
      d4o[(rowBase + rr) * 64 + c4] = s4[src_idx[rowBase + rr] * 64 + c4];
    }
  }
  __syncthreads();

  const int tc = t & 31;
  const int rowg = t >> 5;          // group 0..15: rows {rowg, rowg+16}
  const float* __restrict__ A0 = SP + rowg * 260;
  const float* __restrict__ A1 = SP + (rowg + 16) * 260;
  const float* __restrict__ SV = SP + t * 260;           // t<32 only
  const float* __restrict__ PV = SP + (32 + t) * 260;    // t<32 only

  float acc00 = 0.f, acc01 = 0.f, acc10 = 0.f, acc11 = 0.f, aff = 0.f;
#pragma unroll 4
  for (int d4 = 0; d4 < 64; ++d4) {
    const int dd = d4 * 4;
    const float4 a0 = *(const float4*)&A0[dd];
    const float4 a1 = *(const float4*)&A1[dd];
    float2 b[4];
#pragma unroll
    for (int i2 = 0; i2 < 4; ++i2)
      b[i2] = *(const float2*)&BT[(dd + i2) * 64 + 2 * tc];
    float4 sv, pv;
    if (t < 32) {
      sv = *(const float4*)&SV[dd];
      pv = *(const float4*)&PV[dd];
    }
#pragma unroll
    for (int i2 = 0; i2 < 4; ++i2) {
      const float va0 = ((const float*)&a0)[i2];
      const float va1 = ((const float*)&a1)[i2];
      acc00 = fmaf(va0, b[i2].x, acc00);
      acc01 = fmaf(va0, b[i2].y, acc01);
      acc10 = fmaf(va1, b[i2].x, acc10);
      acc11 = fmaf(va1, b[i2].y, acc11);
      if (t < 32)
        aff = fmaf(((const float*)&sv)[i2], ((const float*)&pv)[i2], aff);
    }
  }
  if (t < 32) affL[t] = aff;
  __syncthreads();

  float sp = softplusf(acc00) + softplusf(acc01) +
             softplusf(acc10) + softplusf(acc11);
  const float av0 = affL[rowg], av1 = affL[rowg + 16];
  int c0 = ((acc00 >= av0) ? 1 : 0) + ((acc01 >= av0) ? 1 : 0);
  int c1 = ((acc10 >= av1) ? 1 : 0) + ((acc11 >= av1) ? 1 : 0);
#pragma unroll
  for (int off = 16; off > 0; off >>= 1) {
    sp += __shfl_down(sp, off, 32);
    c0 += __shfl_down(c0, off, 32);
    c1 += __shfl_down(c1, off, 32);
  }
  if ((t & 31) == 0) {
    cntL[rowg] = c0;
    cntL[rowg + 16] = c1;
    wsum[rowg] = sp;
  }
  __syncthreads();

  if (t < 32) rankPart[(bid & 7) * 1024 + rowBase + t] = cntL[t];
  if (t == 0) {
    float sn = 0.f;
#pragma unroll
    for (int w = 0; w < 16; ++w) sn += wsum[w];
    spNegPart[bid] = sn;
  }
  if (first && t == 0) {
    float ps = 0.f;
#pragma unroll
    for (int r = 0; r < 32; ++r) ps += softplusf(-affL[r]);
    spPosPart[bid >> 3] = ps;
  }
}

// mrr + loss from partials. 1 block. (unchanged, R11)
__global__ __launch_bounds__(256) void k_finalize(
    const int* __restrict__ rankPart, const float* __restrict__ spPosPart,
    const float* __restrict__ spNegPart, float* __restrict__ out) {
  __shared__ float wa[4], wb[4];
  const int t = threadIdx.x;
  float s = 0.f;
  for (int i = t; i < BATCH; i += 256) {
    int rv = 0;
#pragma unroll
    for (int p = 0; p < 8; ++p) rv += rankPart[p * 1024 + i];
    s += 1.f / (float)(rv + 1);
  }
  float l = 0.f;
  if (t < 256) l += spNegPart[t];
  if (t < 32) l += spPosPart[t];
#pragma unroll
  for (int off = 32; off > 0; off >>= 1) {
    s += __shfl_down(s, off, 64);
    l += __shfl_down(l, off, 64);
  }
  if ((t & 63) == 0) { wa[t >> 6] = s; wb[t >> 6] = l; }
  __syncthreads();
  if (t == 0) {
    out[BATCH * 256]     = (wb[0] + wb[1] + wb[2] + wb[3]) * (1.f / 1024.f);
    out[BATCH * 256 + 1] = (wa[0] + wa[1] + wa[2] + wa[3]) * (1.f / 1024.f);
  }
}

extern "C" void kernel_launch(void* const* d_in, const int* in_sizes, int n_in,
                              void* d_out, int out_size, void* d_ws, size_t ws_size,
                              hipStream_t stream) {
  const float* feat   = (const float*)d_in[1];
  const int* src_idx  = (const int*)d_in[2];
  const int* pos_idx  = (const int*)d_in[3];
  const int* neg_idx  = (const int*)d_in[4];
  const int* nb0      = (const int*)d_in[5];
  const int* nb1      = (const int*)d_in[6];
  const int* nb2      = (const int*)d_in[7];
  const float* ws0    = (const float*)d_in[8];
  const float* wn0    = (const float*)d_in[9];
  const float* ws1    = (const float*)d_in[10];
  const float* wn1    = (const float*)d_in[11];

  float* wsf = (float*)d_ws;
  unsigned short* X0 = (unsigned short*)d_ws;       // bf16[393216]
  unsigned short* Y0 = X0 + 393216;                 // bf16[393216]
  float* R       = wsf + 1966080;                   // 3072*256
  float* spPosP  = wsf + 2752512;                   // float[32]
  float* spNegP  = wsf + 2752640;                   // float[256]
  int*   rankP   = (int*)(wsf + 2753664);           // int[8*1024]
  float* out     = (float*)d_out;

  // X0 = bf16(feat@ws0), Y0 = bf16(feat@wn0)
  k_mm<128, 128, 0, false, unsigned short><<<L0 / 6, 512, 0, stream>>>(
      feat, ws0, wn0, X0, 128, 393216);
  // FUSED aggregate + mm2 + norm, v4: 2 nodes/block, 4 blocks/CU resident
  k_aggmm<<<L0 / 2, 512, 0, stream>>>(
      X0, Y0, nb0, nb1, nb2, ws1, wn1, R);
  // 256 blocks = 32 row-tiles x 8 col-tiles; B LDS-staged, NO atomics
  k_neg<<<256, 512, 0, stream>>>(
      R, src_idx, pos_idx, neg_idx, out, rankP, spPosP, spNegP);
  k_finalize<<<1, 256, 0, stream>>>(rankP, spPosP, spNegP, out);
}

// Round 16
// 151.858 us; speedup vs baseline: 1.0266x; 1.0266x over previous
//
#include <hip/hip_runtime.h>
#include <math.h>

// Problem constants (from reference setup_inputs)
#define L0      3072
#define BATCH   1024
#define NNEG    512

// -------- workspace layout (float indices into d_ws) --------
// X0 : bf16[393216]            (feat @ w_self_0, bf16)
// Y0 : bf16[393216]            = X0 + 393216 elems
// R  : float @ 1966080 (3072*256)  layer-1 output, normalized
// spPosPart @ 2752512 (float[32]), spNegPart @ 2752640 (float[256]),
// rankPart @ 2753664 (int[8*1024])

__device__ __forceinline__ float bf2f(unsigned short u) {
  return __uint_as_float(((unsigned)u) << 16);
}
__device__ __forceinline__ void store_out(float v, float* p) { *p = v; }
__device__ __forceinline__ void store_out(float v, unsigned short* p) {
  unsigned x = __float_as_uint(v);                 // f32 -> bf16 RNE
  *p = (unsigned short)((x + 0x7fff + ((x >> 16) & 1)) >> 16);
}

// Half-split matmul, 6 rows x 256 cols per 512-thread block. (unchanged, R7)
template<int K, int AW, int HOFF, bool NORM, typename OutT>
__global__ __launch_bounds__(512) void k_mm(
    const float* __restrict__ Ain,
    const float* __restrict__ W0, const float* __restrict__ W1,
    OutT* __restrict__ Out, const int ldo, const int outHalfOff) {
  __shared__ float AT[6 * AW];
  __shared__ float rs[8][3];
  const int t = threadIdx.x;
  const int base = blockIdx.x * 6;
  {
    const float4* __restrict__ src = (const float4*)(Ain + base * AW);
    float4* __restrict__ dst = (float4*)AT;
    for (int idx = t; idx < 6 * AW / 4; idx += 512) dst[idx] = src[idx];
  }
  __syncthreads();

  const int wave = t >> 6;
  const int half = wave >> 2;
  const int colg = (wave >> 1) & 1;
  const int rowg = wave & 1;
  const int rg = rowg * 3;
  const int col = colg * 64 + (t & 63);
  const float* __restrict__ W = (half ? W1 : W0) + col;
  const float* __restrict__ A0 = AT + rg * AW + half * HOFF;

  float acc[3] = {0.f, 0.f, 0.f};
#pragma unroll 4
  for (int d = 0; d < K; d += 4) {
    float4 a[3];
#pragma unroll
    for (int r = 0; r < 3; ++r) a[r] = *(const float4*)&A0[r * AW + d];
    float w[4];
#pragma unroll
    for (int i2 = 0; i2 < 4; ++i2) w[i2] = W[(d + i2) * 128];
#pragma unroll
    for (int i2 = 0; i2 < 4; ++i2)
#pragma unroll
      for (int r = 0; r < 3; ++r)
        acc[r] = fmaf(((const float*)&a[r])[i2], w[i2], acc[r]);
  }

  float scale[3] = {1.f, 1.f, 1.f};
  if (NORM) {
    float p[3];
#pragma unroll
    for (int r = 0; r < 3; ++r) p[r] = acc[r] * acc[r];
#pragma unroll
    for (int off = 32; off > 0; off >>= 1)
#pragma unroll
      for (int r = 0; r < 3; ++r) p[r] += __shfl_xor(p[r], off, 64);
    if ((t & 63) == 0) { rs[wave][0] = p[0]; rs[wave][1] = p[1]; rs[wave][2] = p[2]; }
    __syncthreads();
#pragma unroll
    for (int r = 0; r < 3; ++r) {
      const float s = rs[rowg][r] + rs[rowg + 2][r] + rs[rowg + 4][r] + rs[rowg + 6][r];
      scale[r] = rsqrtf(fmaxf(s, 1e-12f));
    }
  }
  OutT* __restrict__ O = Out + half * outHalfOff;
#pragma unroll
  for (int r = 0; r < 3; ++r)
    store_out(acc[r] * scale[r], &O[(base + rg + r) * ldo + col]);
}

// FUSED aggregate + mm2 + L2-norm — the R14 BEST (153.1us): v1 structure
// (40 interleaved tasks, balanced 5 tasks/wave, gB/gC/gD staging) + the
// issue-all-then-consume gather prefetch. R15's occupancy experiment (2
// nodes/block, 4 blocks/CU, occ 30->50%) was NULL: dur unchanged ->
// occupancy is not the limiter; balanced task streams matter more.
// d8 chain bit-identical -> H and R bit-identical -> k_neg tie semantics
// untouched.
__global__ __launch_bounds__(512) void k_aggmm(
    const unsigned short* __restrict__ X0, const unsigned short* __restrict__ Y0,
    const int* __restrict__ nb0, const int* __restrict__ nb1,
    const int* __restrict__ nb2,
    const float* __restrict__ ws1, const float* __restrict__ wn1,
    float* __restrict__ R) {
  __shared__ float gB[40][128], gC[40][128], gD[40][128];  // 61.4 KB
  __shared__ float HT[4 * 512];                            // 8 KB
  __shared__ float rs[8][2];
  const int t = threadIdx.x;
  const int wave = t >> 6, lam = t & 63;
  const int base = blockIdx.x * 4;
  const int c8 = lam & 15, sub = lam >> 4;

  // ---- agg phase: 40 tasks, wave-strided, prefetch-then-consume ----
#pragma unroll
  for (int k = 0; k < 5; ++k) {
    const int tau = wave + k * 8;            // 0..39, all distinct
    const int li = tau / 10, j = tau - li * 10;
    const int r = (base + li) * 10 + j;
    int myidx = 0;
    if (lam < 25) myidx = nb2[r * 25 + lam];
    else if (lam == 25) myidx = nb1[r];

    // phase 1: issue ALL loads (7 gather rows + the B/C row) -> ~8 in flight
    float4 raw[7];
#pragma unroll
    for (int m = 0; m < 7; ++m) {
      const int kk = sub + 4 * m;
      const int ridx = __shfl(myidx, kk, 64);
      if (kk < 25) raw[m] = *(const float4*)(Y0 + ridx * 128 + c8 * 8);
    }
    const int r1 = __shfl(myidx, 25, 64);
    float4 rawBC;
    if (sub == 0)      rawBC = *(const float4*)(Y0 + r1 * 128 + c8 * 8);
    else if (sub == 1) rawBC = *(const float4*)(X0 + r1 * 128 + c8 * 8);

    // phase 2: consume in ascending m order (bit-identical chain)
    float d8[8];
#pragma unroll
    for (int e = 0; e < 8; ++e) d8[e] = 0.f;
#pragma unroll
    for (int m = 0; m < 7; ++m) {
      const int kk = sub + 4 * m;
      if (kk < 25) {
        const unsigned short* u = (const unsigned short*)&raw[m];
#pragma unroll
        for (int e = 0; e < 8; ++e) d8[e] += bf2f(u[e]);
      }
    }
#pragma unroll
    for (int e = 0; e < 8; ++e) d8[e] += __shfl_xor(d8[e], 16, 64);
#pragma unroll
    for (int e = 0; e < 8; ++e) d8[e] += __shfl_xor(d8[e], 32, 64);

    if (sub == 0) {
#pragma unroll
      for (int e = 0; e < 8; ++e) gD[tau][c8 * 8 + e] = fmaxf(d8[e] * 0.04f, 0.f);
      const unsigned short* u = (const unsigned short*)&rawBC;
#pragma unroll
      for (int e = 0; e < 8; ++e) gB[tau][c8 * 8 + e] = bf2f(u[e]);
    } else if (sub == 1) {
      const unsigned short* u = (const unsigned short*)&rawBC;
#pragma unroll
      for (int e = 0; e < 8; ++e) gC[tau][c8 * 8 + e] = fmaxf(bf2f(u[e]), 0.f);
    }
  }
  __syncthreads();

  // ---- H-build: 512 threads = 4 nodes x 128 cols, ascending-jj sums ----
  {
    const int li = t >> 7, c = t & 127;
    const int n0 = nb0[base + li];
    float sB = 0.f, sC = 0.f, sD = 0.f;
#pragma unroll
    for (int jj = 0; jj < 10; ++jj) {
      sB += gB[li * 10 + jj][c];
      sC += gC[li * 10 + jj][c];
      sD += gD[li * 10 + jj][c];
    }
    HT[li * 512 + c]       = fmaxf(bf2f(X0[n0 * 128 + c]), 0.f);
    HT[li * 512 + 128 + c] = fmaxf(sB * 0.1f, 0.f);
    HT[li * 512 + 256 + c] = sC * 0.1f;
    HT[li * 512 + 384 + c] = sD * 0.1f;
  }
  __syncthreads();

  // ---- mm2 phase: 4 rows x 256 cols, K=256, identical chain + norm ----
  const int half = wave >> 2;
  const int colg = (wave >> 1) & 1;
  const int rowg = wave & 1;
  const int rg = rowg * 2;
  const int col = colg * 64 + lam;
  const float* __restrict__ W = (half ? wn1 : ws1) + col;
  const float* __restrict__ A0 = HT + rg * 512 + half * 256;

  float acc[2] = {0.f, 0.f};
#pragma unroll 4
  for (int d = 0; d < 256; d += 4) {
    float4 a[2];
#pragma unroll
    for (int r = 0; r < 2; ++r) a[r] = *(const float4*)&A0[r * 512 + d];
    float w[4];
#pragma unroll
    for (int i2 = 0; i2 < 4; ++i2) w[i2] = W[(d + i2) * 128];
#pragma unroll
    for (int i2 = 0; i2 < 4; ++i2)
#pragma unroll
      for (int r = 0; r < 2; ++r)
        acc[r] = fmaf(((const float*)&a[r])[i2], w[i2], acc[r]);
  }

  float p[2];
#pragma unroll
  for (int r = 0; r < 2; ++r) p[r] = acc[r] * acc[r];
#pragma unroll
  for (int off = 32; off > 0; off >>= 1)
#pragma unroll
    for (int r = 0; r < 2; ++r) p[r] += __shfl_xor(p[r], off, 64);
  if (lam == 0) { rs[wave][0] = p[0]; rs[wave][1] = p[1]; }
  __syncthreads();
#pragma unroll
  for (int r = 0; r < 2; ++r) {
    const float s = rs[rowg][r] + rs[rowg + 2][r] + rs[rowg + 4][r] + rs[rowg + 6][r];
    const float scale = rsqrtf(fmaxf(s, 1e-12f));
    R[(base + rg + r) * 256 + half * 128 + col] = acc[r] * scale;
  }
}

__device__ __forceinline__ float softplusf(float x) {
  return fmaxf(x, 0.f) + log1pf(expf(-fabsf(x)));
}

// neg_aff v11 (unchanged from the 153.1 winner). LDS-staged B, zero global
// inner-loop ops, zero global atomics.
__global__ __launch_bounds__(512) void k_neg(
    const float* __restrict__ O,
    const int* __restrict__ src_idx, const int* __restrict__ pos_idx,
    const int* __restrict__ neg_idx,
    float* __restrict__ out_src, int* __restrict__ rankPart,
    float* __restrict__ spPosPart, float* __restrict__ spNegPart) {
  __shared__ float SP[64 * 260];     // rows [0,32) src, [32,64) pos (padded)
  __shared__ float BT[256 * 64];     // d-major transposed neg tile (exact bits)
  __shared__ float affL[32];
  __shared__ int cntL[32];
  __shared__ float wsum[16];
  const int t = threadIdx.x;
  const int bid = blockIdx.x;
  const int rowBase = (bid >> 3) * 32;  // 32 row-tiles of 32
  const int colBase = (bid & 7) * 64;   // 8 col-tiles of 64
  const bool first = ((bid & 7) == 0);

  {
    const float4* __restrict__ s4 = (const float4*)O;
#pragma unroll
    for (int idx = t; idx < 64 * 64; idx += 512) {
      const int row = idx >> 6, c4 = idx & 63;
      const int rid = (row < 32) ? src_idx[rowBase + row]
                                 : pos_idx[rowBase + row - 32];
      *(float4*)&SP[row * 260 + c4 * 4] = s4[rid * 64 + c4];
    }
  }
  {
    const float4* __restrict__ s4 = (const float4*)O;
#pragma unroll
    for (int idx = t; idx < 64 * 64; idx += 512) {
      const int j = idx & 63, c4 = idx >> 6;
      const float4 v = s4[neg_idx[colBase + j] * 64 + c4];
      BT[(4 * c4 + 0) * 64 + j] = v.x;
      BT[(4 * c4 + 1) * 64 + j] = v.y;
      BT[(4 * c4 + 2) * 64 + j] = v.z;
      BT[(4 * c4 + 3) * 64 + j] = v.w;
    }
  }
  if (first) {
    const float4* __restrict__ s4 = (const float4*)O;
    float4* __restrict__ d4o = (float4*)out_src;
#pragma unroll
    for (int idx = t; idx < 32 * 64; idx += 512) {
      const int rr = idx >> 6, c4 = idx & 63;
      d4o[(rowBase + rr) * 64 + c4] = s4[src_idx[rowBase + rr] * 64 + c4];
    }
  }
  __syncthreads();

  const int tc = t & 31;
  const int rowg = t >> 5;          // group 0..15: rows {rowg, rowg+16}
  const float* __restrict__ A0 = SP + rowg * 260;
  const float* __restrict__ A1 = SP + (rowg + 16) * 260;
  const float* __restrict__ SV = SP + t * 260;           // t<32 only
  const float* __restrict__ PV = SP + (32 + t) * 260;    // t<32 only

  float acc00 = 0.f, acc01 = 0.f, acc10 = 0.f, acc11 = 0.f, aff = 0.f;
#pragma unroll 4
  for (int d4 = 0; d4 < 64; ++d4) {
    const int dd = d4 * 4;
    const float4 a0 = *(const float4*)&A0[dd];
    const float4 a1 = *(const float4*)&A1[dd];
    float2 b[4];
#pragma unroll
    for (int i2 = 0; i2 < 4; ++i2)
      b[i2] = *(const float2*)&BT[(dd + i2) * 64 + 2 * tc];
    float4 sv, pv;
    if (t < 32) {
      sv = *(const float4*)&SV[dd];
      pv = *(const float4*)&PV[dd];
    }
#pragma unroll
    for (int i2 = 0; i2 < 4; ++i2) {
      const float va0 = ((const float*)&a0)[i2];
      const float va1 = ((const float*)&a1)[i2];
      acc00 = fmaf(va0, b[i2].x, acc00);
      acc01 = fmaf(va0, b[i2].y, acc01);
      acc10 = fmaf(va1, b[i2].x, acc10);
      acc11 = fmaf(va1, b[i2].y, acc11);
      if (t < 32)
        aff = fmaf(((const float*)&sv)[i2], ((const float*)&pv)[i2], aff);
    }
  }
  if (t < 32) affL[t] = aff;
  __syncthreads();

  float sp = softplusf(acc00) + softplusf(acc01) +
             softplusf(acc10) + softplusf(acc11);
  const float av0 = affL[rowg], av1 = affL[rowg + 16];
  int c0 = ((acc00 >= av0) ? 1 : 0) + ((acc01 >= av0) ? 1 : 0);
  int c1 = ((acc10 >= av1) ? 1 : 0) + ((acc11 >= av1) ? 1 : 0);
#pragma unroll
  for (int off = 16; off > 0; off >>= 1) {
    sp += __shfl_down(sp, off, 32);
    c0 += __shfl_down(c0, off, 32);
    c1 += __shfl_down(c1, off, 32);
  }
  if ((t & 31) == 0) {
    cntL[rowg] = c0;
    cntL[rowg + 16] = c1;
    wsum[rowg] = sp;
  }
  __syncthreads();

  if (t < 32) rankPart[(bid & 7) * 1024 + rowBase + t] = cntL[t];
  if (t == 0) {
    float sn = 0.f;
#pragma unroll
    for (int w = 0; w < 16; ++w) sn += wsum[w];
    spNegPart[bid] = sn;
  }
  if (first && t == 0) {
    float ps = 0.f;
#pragma unroll
    for (int r = 0; r < 32; ++r) ps += softplusf(-affL[r]);
    spPosPart[bid >> 3] = ps;
  }
}

// mrr + loss from partials. 1 block. (unchanged, R11)
__global__ __launch_bounds__(256) void k_finalize(
    const int* __restrict__ rankPart, const float* __restrict__ spPosPart,
    const float* __restrict__ spNegPart, float* __restrict__ out) {
  __shared__ float wa[4], wb[4];
  const int t = threadIdx.x;
  float s = 0.f;
  for (int i = t; i < BATCH; i += 256) {
    int rv = 0;
#pragma unroll
    for (int p = 0; p < 8; ++p) rv += rankPart[p * 1024 + i];
    s += 1.f / (float)(rv + 1);
  }
  float l = 0.f;
  if (t < 256) l += spNegPart[t];
  if (t < 32) l += spPosPart[t];
#pragma unroll
  for (int off = 32; off > 0; off >>= 1) {
    s += __shfl_down(s, off, 64);
    l += __shfl_down(l, off, 64);
  }
  if ((t & 63) == 0) { wa[t >> 6] = s; wb[t >> 6] = l; }
  __syncthreads();
  if (t == 0) {
    out[BATCH * 256]     = (wb[0] + wb[1] + wb[2] + wb[3]) * (1.f / 1024.f);
    out[BATCH * 256 + 1] = (wa[0] + wa[1] + wa[2] + wa[3]) * (1.f / 1024.f);
  }
}

extern "C" void kernel_launch(void* const* d_in, const int* in_sizes, int n_in,
                              void* d_out, int out_size, void* d_ws, size_t ws_size,
                              hipStream_t stream) {
  const float* feat   = (const float*)d_in[1];
  const int* src_idx  = (const int*)d_in[2];
  const int* pos_idx  = (const int*)d_in[3];
  const int* neg_idx  = (const int*)d_in[4];
  const int* nb0      = (const int*)d_in[5];
  const int* nb1      = (const int*)d_in[6];
  const int* nb2      = (const int*)d_in[7];
  const float* ws0    = (const float*)d_in[8];
  const float* wn0    = (const float*)d_in[9];
  const float* ws1    = (const float*)d_in[10];
  const float* wn1    = (const float*)d_in[11];

  float* wsf = (float*)d_ws;
  unsigned short* X0 = (unsigned short*)d_ws;       // bf16[393216]
  unsigned short* Y0 = X0 + 393216;                 // bf16[393216]
  float* R       = wsf + 1966080;                   // 3072*256
  float* spPosP  = wsf + 2752512;                   // float[32]
  float* spNegP  = wsf + 2752640;                   // float[256]
  int*   rankP   = (int*)(wsf + 2753664);           // int[8*1024]
  float* out     = (float*)d_out;

  // X0 = bf16(feat@ws0), Y0 = bf16(feat@wn0)
  k_mm<128, 128, 0, false, unsigned short><<<L0 / 6, 512, 0, stream>>>(
      feat, ws0, wn0, X0, 128, 393216);
  // FUSED aggregate + mm2 + norm (R14 best: v1 structure + gather prefetch)
  k_aggmm<<<L0 / 4, 512, 0, stream>>>(
      X0, Y0, nb0, nb1, nb2, ws1, wn1, R);
  // 256 blocks = 32 row-tiles x 8 col-tiles; B LDS-staged, NO atomics
  k_neg<<<256, 512, 0, stream>>>(
      R, src_idx, pos_idx, neg_idx, out, rankP, spPosP, spNegP);
  k_finalize<<<1, 256, 0, stream>>>(rankP, spPosP, spNegP, out);
}